// Round 7
// baseline (227.387 us; speedup 1.0000x reference)
//
#include <hip/hip_runtime.h>
#include <stdint.h>

typedef _Float16 f16;
typedef _Float16 f16x8 __attribute__((ext_vector_type(8)));
typedef _Float16 f16x4 __attribute__((ext_vector_type(4)));
typedef float f32x4 __attribute__((ext_vector_type(4)));
typedef unsigned uint2v __attribute__((ext_vector_type(2)));

#define AS1 __attribute__((address_space(1)))
#define AS3 __attribute__((address_space(3)))

#if __has_builtin(__builtin_amdgcn_exp2f)
#define EXP2(x) __builtin_amdgcn_exp2f(x)
#else
#define EXP2(x) exp2f(x)
#endif

__device__ __forceinline__ void gl_lds16(const void* g, void* l) {
  __builtin_amdgcn_global_load_lds((const AS1 uint32_t*)g, (AS3 uint32_t*)l, 16, 0, 0);
}

// sum over the 4 lanes {l, l^16, l^32, l^48} holding the same query row
// (proven: inline-asm permlane swaps with conservative hazard nops)
__device__ __forceinline__ unsigned quadsum_u(unsigned v) {
  unsigned a = v, b = v;
  asm("s_nop 1\n\tv_permlane16_swap_b32 %0, %1" : "+v"(a), "+v"(b));
  unsigned s = a + b;
  unsigned a2 = s, b2 = s;
  asm("s_nop 1\n\tv_permlane32_swap_b32 %0, %1" : "+v"(a2), "+v"(b2));
  return a2 + b2;
}
__device__ __forceinline__ float quadsum_f(float v) {
  float a = v, b = v;
  asm("s_nop 1\n\tv_permlane16_swap_b32 %0, %1" : "+v"(a), "+v"(b));
  float s = a + b;
  float a2 = s, b2 = s;
  asm("s_nop 1\n\tv_permlane32_swap_b32 %0, %1" : "+v"(a2), "+v"(b2));
  return a2 + b2;
}

// packed-u16 count: per half, returns (k >= cm1+1) ? 1 : 0. (proven in R3)
__device__ __forceinline__ unsigned pk_cnt_ge(unsigned k, unsigned cm1, unsigned ones) {
  unsigned d;
  asm("v_pk_sub_u16 %0, %1, %2 clamp" : "=v"(d) : "v"(k), "v"(cm1));
  asm("v_pk_min_u16 %0, %1, %2" : "=v"(d) : "v"(d), "v"(ones));
  return d;
}

// pack two floats to f16x2 bits (RTZ), returned as u32
__device__ __forceinline__ unsigned cvt_pk_u32(float a, float b) {
  return __builtin_bit_cast(unsigned, __builtin_amdgcn_cvt_pkrtz(a, b));
}

// ---------- fused prep: z=0..3 -> W transpose+cvt (Wo scaled 1/16); z=4 -> x cvt ----------
__global__ void k_prep(const float* __restrict__ x,
                       const float* __restrict__ Wq, const float* __restrict__ Wk,
                       const float* __restrict__ Wv, const float* __restrict__ Wo,
                       f16* __restrict__ xh,
                       f16* __restrict__ Wqt, f16* __restrict__ Wkt,
                       f16* __restrict__ Wvt, f16* __restrict__ Wot) {
  __shared__ __align__(16) f16 lt[64][72];
  const int t = threadIdx.x;
  if (blockIdx.z == 4) {
    int bid2 = blockIdx.y * 16 + blockIdx.x;
    #pragma unroll 4
    for (int it = 0; it < 16; ++it) {
      int i = ((bid2 * 16 + it) * 256 + t) * 4;
      float4 v = *(const float4*)(x + i);
      f16x4 o = { (f16)v.x, (f16)v.y, (f16)v.z, (f16)v.w };
      *(f16x4*)(xh + i) = o;
    }
    return;
  }
  const float* src; f16* dst; float scl;
  switch (blockIdx.z) {
    case 0: src = Wq; dst = Wqt; scl = 1.0f; break;
    case 1: src = Wk; dst = Wkt; scl = 1.0f; break;
    case 2: src = Wv; dst = Wvt; scl = 1.0f; break;
    default: src = Wo; dst = Wot; scl = 0.0625f; break;   // fold attn 1/16 into Wo
  }
  int n0 = blockIdx.x * 64, k0 = blockIdx.y * 64;
  int kk = t >> 4;
  int nn = (t & 15) * 4;
  #pragma unroll
  for (int p = 0; p < 4; ++p) {
    int k = kk + p * 16;
    float4 v = *(const float4*)(src + (size_t)(k0 + k) * 1024 + n0 + nn);
    lt[nn + 0][k] = (f16)(v.x * scl);
    lt[nn + 1][k] = (f16)(v.y * scl);
    lt[nn + 2][k] = (f16)(v.z * scl);
    lt[nn + 3][k] = (f16)(v.w * scl);
  }
  __syncthreads();
  int row = t >> 2;
  int kp = (t & 3) * 16;
  f16* d = dst + (size_t)(n0 + row) * 1024 + k0 + kp;
  *(f16x8*)d       = *(const f16x8*)&lt[row][kp];
  *(f16x8*)(d + 8) = *(const f16x8*)&lt[row][kp + 8];
}

// ---------------- GEMM: C(TMxN128 per block) = A * Bt^T ----------------
// MODE 0, TM=128: A=xh; Bt0/1/2=Wqt/Wkt/Wvt; N=3072; grid(24,32).
//   LDS: As+Bs (32 KiB) UNION'd with EP (36 KiB, epilogue-only, barrier-guarded).
// MODE 2, TM=64:  A=p0, A2=p1 (attention halves; staged as p0+p1); Bt0=Wot/16;
//                 out0 = f32 row-major. grid(8,64).
template<int MODE, int TM>
__global__ __launch_bounds__(256, 3)
void k_gemm(const f16* __restrict__ A, const f16* __restrict__ Bt0,
            const f16* __restrict__ A2, const f16* __restrict__ Bt2,
            const f16* __restrict__ Bt1,
            void* __restrict__ out0, void* __restrict__ out1, void* __restrict__ out2) {
  constexpr int SMEM_MAIN = TM * 64 * 2 + 128 * 64 * 2;
  constexpr int SMEM_EP = (MODE == 0) ? 4 * 64 * 72 * 2 : 0;
  constexpr int SMEM_SZ = SMEM_EP > SMEM_MAIN ? SMEM_EP : SMEM_MAIN;
  __shared__ __align__(16) char smem[SMEM_SZ];
  f16* As = (f16*)smem;
  f16* Bs = (f16*)(smem + TM * 64 * 2);
  f16* EPb = (f16*)smem;
  const int n0 = blockIdx.x * 128, m0 = blockIdx.y * TM;
  const int tid = threadIdx.x, wave = tid >> 6, lane = tid & 63;
  const int l15 = lane & 15, quad = lane >> 4;
  const int wm = (wave >> 1) * (TM / 2), wn = (wave & 1) * 64;
  constexpr int NI = TM / 32;
  constexpr int PA = TM / 32;
  const f16* Bsrc = Bt0;
  int nb = n0;
  if (MODE == 0) {
    if (n0 >= 2048)      { Bsrc = Bt2; nb = n0 - 2048; }
    else if (n0 >= 1024) { Bsrc = Bt1; nb = n0 - 1024; }
  }
  f32x4 acc[NI][4] = {};
  const int sr = lane >> 3, sg = lane & 7;
  const int gl = sg ^ sr;
  const f16* ap[PA];
  const f16* ap2[PA];
  const f16* bp[4];
  #pragma unroll
  for (int p = 0; p < PA; ++p) {
    size_t off = (size_t)(m0 + wave * (TM / 4) + p * 8 + sr) * 1024 + gl * 8;
    ap[p] = A + off;
    if (MODE == 2) ap2[p] = A2 + off;
  }
  #pragma unroll
  for (int p = 0; p < 4; ++p)
    bp[p] = Bsrc + (size_t)(nb + wave * 32 + p * 8 + sr) * 1024 + gl * 8;

  for (int kt = 0; kt < 16; ++kt) {
    __syncthreads();
    #pragma unroll
    for (int p = 0; p < PA; ++p) {
      if (MODE == 2) {
        // stage A = p0 + p1 (combine attention halves in-flight)
        f16x8 a0 = *(const f16x8*)ap[p];
        f16x8 a1 = *(const f16x8*)ap2[p];
        *(f16x8*)&As[(wave * (TM / 4) + p * 8) * 64 + lane * 8] = a0 + a1;
        ap2[p] += 64;
      } else {
        gl_lds16(ap[p], &As[(wave * (TM / 4) + p * 8) * 64]);
      }
      ap[p] += 64;
    }
    #pragma unroll
    for (int p = 0; p < 4; ++p) {
      gl_lds16(bp[p], &Bs[(wave * 32 + p * 8) * 64]);
      bp[p] += 64;
    }
    __syncthreads();
    #pragma unroll
    for (int ks = 0; ks < 2; ++ks) {
      f16x8 af[NI], bf[4];
      #pragma unroll
      for (int i = 0; i < NI; ++i) {
        int row = wm + i * 16 + l15;
        int g2 = (ks * 4 + quad) ^ (row & 7);
        af[i] = *(const f16x8*)&As[row * 64 + g2 * 8];
      }
      #pragma unroll
      for (int j = 0; j < 4; ++j) {
        int row = wn + j * 16 + l15;
        int g2 = (ks * 4 + quad) ^ (row & 7);
        bf[j] = *(const f16x8*)&Bs[row * 64 + g2 * 8];
      }
      #pragma unroll
      for (int i = 0; i < NI; ++i)
        #pragma unroll
        for (int j = 0; j < 4; ++j)
          acc[i][j] = __builtin_amdgcn_mfma_f32_16x16x32_f16(af[i], bf[j], acc[i][j], 0, 0, 0);
    }
  }

  if (MODE == 0) {
    if (n0 < 2048) {
      __syncthreads();   // all waves done reading As/Bs before EP overlays them
      f16* ep = &EPb[wave * 64 * 72];
      #pragma unroll
      for (int i = 0; i < NI; ++i)
        #pragma unroll
        for (int j = 0; j < 4; ++j)
          #pragma unroll
          for (int r = 0; r < 4; ++r)
            ep[(i * 16 + quad * 4 + r) * 72 + j * 16 + l15] = (f16)acc[i][j][r];
      f16* dst = (n0 < 1024) ? (f16*)out0 : (f16*)out1;
      const int hh = ((n0 + wn) & 1023) >> 6;
      const int r8 = lane >> 3, cg = lane & 7;
      #pragma unroll
      for (int it = 0; it < 8; ++it) {
        int row = it * 8 + r8;
        f16x8 vv = *(const f16x8*)&ep[row * 72 + cg * 8];
        int m = m0 + wm + row;
        int b = m >> 10, t = m & 1023;
        *(f16x8*)&dst[(size_t)((b * 16 + hh) * 1024 + t) * 64 + cg * 8] = vv;
      }
    } else {
      #pragma unroll
      for (int i = 0; i < NI; ++i)
        #pragma unroll
        for (int j = 0; j < 4; ++j) {
          int mb = m0 + wm + i * 16 + quad * 4;
          int b = mb >> 10, t = mb & 1023;
          int n = n0 + wn + j * 16 + l15;
          int nn2 = n & 1023, hh = nn2 >> 6, d = nn2 & 63;
          f16x4 vv = { (f16)acc[i][j][0], (f16)acc[i][j][1], (f16)acc[i][j][2], (f16)acc[i][j][3] };
          *(f16x4*)((f16*)out2 + ((size_t)(b * 16 + hh) * 64 + d) * 1024 + t) = vv;
        }
    }
  } else {
    #pragma unroll
    for (int i = 0; i < NI; ++i)
      #pragma unroll
      for (int j = 0; j < 4; ++j)
        #pragma unroll
        for (int r = 0; r < 4; ++r) {
          int m = m0 + wm + i * 16 + quad * 4 + r;
          int n = n0 + wn + j * 16 + l15;
          ((float*)out0)[(size_t)m * 1024 + n] = acc[i][j][r];
        }
  }
}

// ---------------- fused sparse attention (half the chunks per block) ----------------
// S computed TRANSPOSED (mfma(K,Q)). Top-32 via 13-step packed-u16 bisection
// (proven R3/R5). R7: K double-buffered, V SINGLE-buffered (load issued at chunk
// top, completes under QK/bisect/softmax) -> LDS 40K -> 4 blocks/CU.
// 3 barriers/chunk with counted vmcnt (never 0 until drain).
// XCD-bijective block swizzle (proven R6: FETCH 74->16.7 MB).
__global__ __launch_bounds__(256, 4)
void k_attn(const f16* __restrict__ Q16, const f16* __restrict__ K16, const f16* __restrict__ Vt16,
            const float* __restrict__ imp, const float* __restrict__ temps,
            f16* __restrict__ part0, f16* __restrict__ part1) {
  __shared__ __align__(16) f16 Qs[64 * 64];
  __shared__ __align__(16) f16 KsB[2][64 * 64];
  __shared__ __align__(16) f16 Vs[64 * 64];
  __shared__ __align__(16) f16 Ps[64 * 64];

  // XCD swizzle (grid = 2048 = 8 * 256, bijective)
  const int orig = ((int)blockIdx.x & 7) * 256 + ((int)blockIdx.x >> 3);
  const int bid = orig & 1023;
  const int half = orig >> 10;
  const int b = bid >> 8, h = (bid >> 4) & 15, qt = bid & 15;
  const int bh = b * 16 + h;
  const int tid = threadIdx.x, wave = tid >> 6, lane = tid & 63;
  const int l15 = lane & 15, quad = lane >> 4;

  // per-lane query-row scale (row m = wave*16 + l15)
  float sc = (0.125f * 1.44269504088896340736f) / fminf(fmaxf(temps[bh], 0.1f), 100.0f);
  const int tq = qt * 64 + wave * 16 + l15;
  float is = imp[(size_t)(b * 1024 + tq) * 16 + h];
  float s1 = 1.0f / (1.0f + __expf(-is));
  float mwv = 1.0f / (1.0f + __expf(-(s1 - 0.5f) * 10.0f));
  const float rs = sc * mwv;

  const unsigned vones = 0x00010001u;   // packed (1,1) for pk_min

  const int sr = lane >> 3, sg = lane & 7;
  const int gls = sg ^ sr;
  const size_t qoff = ((size_t)bh * 1024 + qt * 64) * 64;
  // prologue: Q (2 loads) + K(0) (2 loads) in flight
  gl_lds16(Q16 + qoff + (size_t)(wave * 16 + sr) * 64 + gls * 8,     &Qs[(wave * 16) * 64]);
  gl_lds16(Q16 + qoff + (size_t)(wave * 16 + 8 + sr) * 64 + gls * 8, &Qs[(wave * 16 + 8) * 64]);

  const size_t kbase = (size_t)bh * 1024 * 64;
  const size_t vbase = (size_t)bh * 64 * 1024;
  const f16* kp0 = K16 + kbase + (size_t)(half * 512 + wave * 16 + sr) * 64 + gls * 8;
  const f16* kp1 = kp0 + 8 * 64;
  const f16* vp0 = Vt16 + vbase + (size_t)(wave * 16 + sr) * 1024 + half * 512 + gls * 8;
  const f16* vp1 = vp0 + 8 * 1024;

  gl_lds16(kp0, &KsB[0][(wave * 16) * 64]);
  gl_lds16(kp1, &KsB[0][(wave * 16 + 8) * 64]);
  kp0 += 4096; kp1 += 4096;

  // hoisted P-store bases: value (m = wave*16+l15, c = j*16+quad*4+r) lands at
  // Ps[m*64 + ((c>>3)^(m&7))*8 + (c&7)]; the 4 r's are contiguous -> ds_write_b64
  const int mrow = wave * 16 + l15;
  f16* pst[4];
  #pragma unroll
  for (int j = 0; j < 4; ++j)
    pst[j] = &Ps[mrow * 64 + (((j * 2 + (quad >> 1)) ^ (l15 & 7)) * 8 + (quad & 1) * 4)];

  f32x4 oacc[4] = {};

  for (int ck = 0; ck < 8; ++ck) {
    const int cur = ck & 1, nxt = cur ^ 1;
    // B1: all waves finished PV(ck-1) (Vs free) and QK(ck-1) (KsB[nxt] free)
    __builtin_amdgcn_s_barrier();
    // issue V(ck) -> Vs (single buffer), then K(ck+1) -> KsB[nxt]
    gl_lds16(vp0, &Vs[(wave * 16) * 64]);
    gl_lds16(vp1, &Vs[(wave * 16 + 8) * 64]);
    vp0 += 64; vp1 += 64;
    if (ck < 7) {
      gl_lds16(kp0, &KsB[nxt][(wave * 16) * 64]);
      gl_lds16(kp1, &KsB[nxt][(wave * 16 + 8) * 64]);
      kp0 += 4096; kp1 += 4096;
      // K(ck) (and Q) drained; V(ck):2 + K(ck+1):2 stay in flight
      asm volatile("s_waitcnt vmcnt(4)" ::: "memory");
    } else {
      // only V(7):2 in flight; K(7) drained
      asm volatile("s_waitcnt vmcnt(2)" ::: "memory");
    }
    __builtin_amdgcn_sched_barrier(0);
    // B2: every wave's K(ck) staging visible
    __builtin_amdgcn_s_barrier();

    const f16* Kc = &KsB[cur][0];

    // ---- S^T = K x Q^T : sacc[j][r] = S[c = j*16+quad*4+r][m = l15] ----
    f32x4 sacc[4] = {};
    #pragma unroll
    for (int ks = 0; ks < 2; ++ks) {
      int qr = wave * 16 + l15;
      int gq = (ks * 4 + quad) ^ (qr & 7);
      f16x8 bq = *(const f16x8*)&Qs[qr * 64 + gq * 8];
      #pragma unroll
      for (int j = 0; j < 4; ++j) {
        int kr = j * 16 + l15;
        int gk = (ks * 4 + quad) ^ (kr & 7);
        f16x8 ak = *(const f16x8*)&Kc[kr * 64 + gk * 8];
        sacc[j] = __builtin_amdgcn_mfma_f32_16x16x32_f16(ak, bq, sacc[j], 0, 0, 0);
      }
    }

    // ---- biased clamp: xx = med3(fma(s, rs, 192), 132, 252) in [132,252] ----
    float xx[4][4];
    #pragma unroll
    for (int j = 0; j < 4; ++j)
      #pragma unroll
      for (int r = 0; r < 4; ++r)
        xx[j][r] = __builtin_amdgcn_fmed3f(__builtin_fmaf(sacc[j][r], rs, 192.0f), 132.0f, 252.0f);

    // ---- pack 16 keys to 8 x u16x2: k16 = (bits(xx) >> 10) & 0xffff ----
    unsigned pk16[8];
    #pragma unroll
    for (int j = 0; j < 4; ++j) {
      unsigned a0 = __builtin_bit_cast(unsigned, xx[j][0]) >> 10;
      unsigned a1 = __builtin_bit_cast(unsigned, xx[j][1]) >> 10;
      unsigned a2 = __builtin_bit_cast(unsigned, xx[j][2]) >> 10;
      unsigned a3 = __builtin_bit_cast(unsigned, xx[j][3]) >> 10;
      pk16[j * 2 + 0] = __builtin_amdgcn_perm(a1, a0, 0x05040100);
      pk16[j * 2 + 1] = __builtin_amdgcn_perm(a3, a2, 0x05040100);
    }

    // ---- top-32 threshold: 13-step bisection, packed counting ----
    unsigned tkp = 0xC000C000u;
    #pragma unroll
    for (int bit = 12; bit >= 0; --bit) {
      const unsigned cand = tkp | ((1u << bit) | (1u << (bit + 16)));
      const unsigned cm1 = cand - 0x00010001u;   // halves >= 0xC001, no inter-half borrow
      unsigned acc = 0;
      #pragma unroll
      for (int i = 0; i < 8; ++i)
        acc += pk_cnt_ge(pk16[i], cm1, vones);   // halves accumulate independently (<= 8)
      unsigned q = quadsum_u(acc);               // packed quad-sum: halves <= 32
      unsigned tot2 = q + (q << 16);             // top half = lo+hi (<= 64, no overflow)
      tkp = (tot2 >= (32u << 16)) ? cand : tkp;
    }
    const unsigned tk32 = 0x43000000u | ((tkp & 0x1fffu) << 10);

    // ---- masked softmax (masked -> exp2(0)=1, exact) ----
    float e[4][4];
    #pragma unroll
    for (int j = 0; j < 4; ++j)
      #pragma unroll
      for (int r = 0; r < 4; ++r) {
        float sel = (__builtin_bit_cast(unsigned, xx[j][r]) >= tk32) ? xx[j][r] : 192.0f;
        e[j][r] = EXP2(sel - 192.0f);
      }
    float dsum = ((e[0][0] + e[0][1]) + (e[0][2] + e[0][3]))
               + ((e[1][0] + e[1][1]) + (e[1][2] + e[1][3]))
               + ((e[2][0] + e[2][1]) + (e[2][2] + e[2][3]))
               + ((e[3][0] + e[3][1]) + (e[3][2] + e[3][3]));
    dsum = quadsum_f(dsum);
    const float dinv = __builtin_amdgcn_rcpf(dsum);

    // ---- P -> f16 (cvt_pkrtz pairs) into A-operand layout, 4x ds_write_b64 ----
    #pragma unroll
    for (int j = 0; j < 4; ++j) {
      uint2v pw = { cvt_pk_u32(e[j][0] * dinv, e[j][1] * dinv),
                    cvt_pk_u32(e[j][2] * dinv, e[j][3] * dinv) };
      *(f16x4*)pst[j] = __builtin_bit_cast(f16x4, pw);
    }

    // own V(ck) complete (only K(ck+1) outstanding); B3 publishes all waves' V
    if (ck < 7) {
      asm volatile("s_waitcnt vmcnt(2)" ::: "memory");
    } else {
      asm volatile("s_waitcnt vmcnt(0)" ::: "memory");
    }
    __builtin_amdgcn_sched_barrier(0);
    __builtin_amdgcn_s_barrier();

    // ---- O += P x V ----
    #pragma unroll
    for (int ks = 0; ks < 2; ++ks) {
      int row = wave * 16 + l15;
      int g2 = (ks * 4 + quad) ^ (row & 7);
      f16x8 ap2 = *(const f16x8*)&Ps[row * 64 + g2 * 8];
      #pragma unroll
      for (int j = 0; j < 4; ++j) {
        int rn = j * 16 + l15;
        int gn = (ks * 4 + quad) ^ (rn & 7);
        f16x8 bv = *(const f16x8*)&Vs[rn * 64 + gn * 8];
        oacc[j] = __builtin_amdgcn_mfma_f32_16x16x32_f16(ap2, bv, oacc[j], 0, 0, 0);
      }
    }
  }

  // raw partial; 1/16 is folded into Wot, halves combined in k_gemm<2> staging
  f16* pd = half ? part1 : part0;
  #pragma unroll
  for (int j = 0; j < 4; ++j)
    #pragma unroll
    for (int r = 0; r < 4; ++r) {
      int m = wave * 16 + quad * 4 + r;
      int t = qt * 64 + m;
      int d = j * 16 + l15;
      pd[(size_t)(b * 1024 + t) * 1024 + h * 64 + d] = (f16)oacc[j][r];
    }
}

extern "C" void kernel_launch(void* const* d_in, const int* in_sizes, int n_in,
                              void* d_out, int out_size, void* d_ws, size_t ws_size,
                              hipStream_t stream) {
  (void)in_sizes; (void)n_in; (void)out_size; (void)ws_size;
  const float* x     = (const float*)d_in[0];
  const float* imp   = (const float*)d_in[1];
  const float* temps = (const float*)d_in[2];
  const float* Wq    = (const float*)d_in[3];
  const float* Wk    = (const float*)d_in[4];
  const float* Wv    = (const float*)d_in[5];
  const float* Wo    = (const float*)d_in[6];
  float* out = (float*)d_out;

  char* w = (char*)d_ws;   // 48 MB
  f16* xh   = (f16*)w; w += (size_t)4096 * 1024 * 2;   // reused as attn part0
  f16* Wqt  = (f16*)w; w += (size_t)1024 * 1024 * 2;
  f16* Wkt  = (f16*)w; w += (size_t)1024 * 1024 * 2;
  f16* Wvt  = (f16*)w; w += (size_t)1024 * 1024 * 2;
  f16* Wot  = (f16*)w; w += (size_t)1024 * 1024 * 2;   // pre-scaled by 1/16
  f16* Q16  = (f16*)w; w += (size_t)4096 * 1024 * 2;
  f16* K16  = (f16*)w; w += (size_t)4096 * 1024 * 2;
  f16* Vt16 = (f16*)w; w += (size_t)4096 * 1024 * 2;
  f16* O16  = (f16*)w; w += (size_t)4096 * 1024 * 2;   // attn part1

  k_prep<<<dim3(16, 16, 5), dim3(256), 0, stream>>>(x, Wq, Wk, Wv, Wo, xh, Wqt, Wkt, Wvt, Wot);
  k_gemm<0, 128><<<dim3(24, 32), dim3(256), 0, stream>>>(xh, Wqt, nullptr, Wvt, Wkt,
                                                         (void*)Q16, (void*)K16, (void*)Vt16);
  k_attn<<<dim3(2048), dim3(256), 0, stream>>>(Q16, K16, Vt16, imp, temps, xh, O16);
  k_gemm<2, 64><<<dim3(8, 64), dim3(256), 0, stream>>>(xh, Wot, O16, nullptr, nullptr,
                                                       (void*)out, nullptr, nullptr);
}

// Round 8
// 226.806 us; speedup vs baseline: 1.0026x; 1.0026x over previous
//
#include <hip/hip_runtime.h>
#include <stdint.h>

typedef _Float16 f16;
typedef _Float16 f16x8 __attribute__((ext_vector_type(8)));
typedef _Float16 f16x4 __attribute__((ext_vector_type(4)));
typedef float f32x4 __attribute__((ext_vector_type(4)));
typedef unsigned uint4v __attribute__((ext_vector_type(4)));

#define AS1 __attribute__((address_space(1)))
#define AS3 __attribute__((address_space(3)))

#if __has_builtin(__builtin_amdgcn_exp2f)
#define EXP2(x) __builtin_amdgcn_exp2f(x)
#else
#define EXP2(x) exp2f(x)
#endif

__device__ __forceinline__ void gl_lds16(const void* g, void* l) {
  __builtin_amdgcn_global_load_lds((const AS1 uint32_t*)g, (AS3 uint32_t*)l, 16, 0, 0);
}

// sum over the 4 lanes {l, l^16, l^32, l^48} holding the same query row
// (proven: inline-asm permlane swaps with conservative hazard nops)
__device__ __forceinline__ unsigned quadsum_u(unsigned v) {
  unsigned a = v, b = v;
  asm("s_nop 1\n\tv_permlane16_swap_b32 %0, %1" : "+v"(a), "+v"(b));
  unsigned s = a + b;
  unsigned a2 = s, b2 = s;
  asm("s_nop 1\n\tv_permlane32_swap_b32 %0, %1" : "+v"(a2), "+v"(b2));
  return a2 + b2;
}
__device__ __forceinline__ float quadsum_f(float v) {
  float a = v, b = v;
  asm("s_nop 1\n\tv_permlane16_swap_b32 %0, %1" : "+v"(a), "+v"(b));
  float s = a + b;
  float a2 = s, b2 = s;
  asm("s_nop 1\n\tv_permlane32_swap_b32 %0, %1" : "+v"(a2), "+v"(b2));
  return a2 + b2;
}

// packed-u16 count: per half, returns (k >= cm1+1) ? 1 : 0. (proven in R3)
__device__ __forceinline__ unsigned pk_cnt_ge(unsigned k, unsigned cm1, unsigned ones) {
  unsigned d;
  asm("v_pk_sub_u16 %0, %1, %2 clamp" : "=v"(d) : "v"(k), "v"(cm1));
  asm("v_pk_min_u16 %0, %1, %2" : "=v"(d) : "v"(d), "v"(ones));
  return d;
}

// pack two floats to f16x2 bits (RTZ), returned as u32
__device__ __forceinline__ unsigned cvt_pk_u32(float a, float b) {
  return __builtin_bit_cast(unsigned, __builtin_amdgcn_cvt_pkrtz(a, b));
}

// ---------- fused prep: z=0..3 -> W transpose+cvt (Wo scaled 1/16); z=4 -> x cvt ----------
__global__ void k_prep(const float* __restrict__ x,
                       const float* __restrict__ Wq, const float* __restrict__ Wk,
                       const float* __restrict__ Wv, const float* __restrict__ Wo,
                       f16* __restrict__ xh,
                       f16* __restrict__ Wqt, f16* __restrict__ Wkt,
                       f16* __restrict__ Wvt, f16* __restrict__ Wot) {
  __shared__ __align__(16) f16 lt[64][72];
  const int t = threadIdx.x;
  if (blockIdx.z == 4) {
    int bid2 = blockIdx.y * 16 + blockIdx.x;
    #pragma unroll 4
    for (int it = 0; it < 16; ++it) {
      int i = ((bid2 * 16 + it) * 256 + t) * 4;
      float4 v = *(const float4*)(x + i);
      f16x4 o = { (f16)v.x, (f16)v.y, (f16)v.z, (f16)v.w };
      *(f16x4*)(xh + i) = o;
    }
    return;
  }
  const float* src; f16* dst; float scl;
  switch (blockIdx.z) {
    case 0: src = Wq; dst = Wqt; scl = 1.0f; break;
    case 1: src = Wk; dst = Wkt; scl = 1.0f; break;
    case 2: src = Wv; dst = Wvt; scl = 1.0f; break;
    default: src = Wo; dst = Wot; scl = 0.0625f; break;   // fold attn 1/16 into Wo
  }
  int n0 = blockIdx.x * 64, k0 = blockIdx.y * 64;
  int kk = t >> 4;
  int nn = (t & 15) * 4;
  #pragma unroll
  for (int p = 0; p < 4; ++p) {
    int k = kk + p * 16;
    float4 v = *(const float4*)(src + (size_t)(k0 + k) * 1024 + n0 + nn);
    lt[nn + 0][k] = (f16)(v.x * scl);
    lt[nn + 1][k] = (f16)(v.y * scl);
    lt[nn + 2][k] = (f16)(v.z * scl);
    lt[nn + 3][k] = (f16)(v.w * scl);
  }
  __syncthreads();
  int row = t >> 2;
  int kp = (t & 3) * 16;
  f16* d = dst + (size_t)(n0 + row) * 1024 + k0 + kp;
  *(f16x8*)d       = *(const f16x8*)&lt[row][kp];
  *(f16x8*)(d + 8) = *(const f16x8*)&lt[row][kp + 8];
}

// ---------------- GEMM: C(TMxN128 per block) = A * Bt^T ----------------
// MODE 0, TM=128: A=xh; Bt0/1/2=Wqt/Wkt/Wvt; N=3072; grid(24,32).
//   LDS: As+Bs (32 KiB) UNION'd with EP (36 KiB, epilogue-only, barrier-guarded).
// MODE 2, TM=64:  A=p0, A2=p1 (attention halves; staged as p0+p1); Bt0=Wot/16;
//                 out0 = f32 row-major. grid(8,64).
template<int MODE, int TM>
__global__ __launch_bounds__(256, 3)
void k_gemm(const f16* __restrict__ A, const f16* __restrict__ Bt0,
            const f16* __restrict__ A2, const f16* __restrict__ Bt2,
            const f16* __restrict__ Bt1,
            void* __restrict__ out0, void* __restrict__ out1, void* __restrict__ out2) {
  constexpr int SMEM_MAIN = TM * 64 * 2 + 128 * 64 * 2;
  constexpr int SMEM_EP = (MODE == 0) ? 4 * 64 * 72 * 2 : 0;
  constexpr int SMEM_SZ = SMEM_EP > SMEM_MAIN ? SMEM_EP : SMEM_MAIN;
  __shared__ __align__(16) char smem[SMEM_SZ];
  f16* As = (f16*)smem;
  f16* Bs = (f16*)(smem + TM * 64 * 2);
  f16* EPb = (f16*)smem;
  const int n0 = blockIdx.x * 128, m0 = blockIdx.y * TM;
  const int tid = threadIdx.x, wave = tid >> 6, lane = tid & 63;
  const int l15 = lane & 15, quad = lane >> 4;
  const int wm = (wave >> 1) * (TM / 2), wn = (wave & 1) * 64;
  constexpr int NI = TM / 32;
  constexpr int PA = TM / 32;
  const f16* Bsrc = Bt0;
  int nb = n0;
  if (MODE == 0) {
    if (n0 >= 2048)      { Bsrc = Bt2; nb = n0 - 2048; }
    else if (n0 >= 1024) { Bsrc = Bt1; nb = n0 - 1024; }
  }
  f32x4 acc[NI][4] = {};
  const int sr = lane >> 3, sg = lane & 7;
  const int gl = sg ^ sr;
  const f16* ap[PA];
  const f16* ap2[PA];
  const f16* bp[4];
  #pragma unroll
  for (int p = 0; p < PA; ++p) {
    size_t off = (size_t)(m0 + wave * (TM / 4) + p * 8 + sr) * 1024 + gl * 8;
    ap[p] = A + off;
    if (MODE == 2) ap2[p] = A2 + off;
  }
  #pragma unroll
  for (int p = 0; p < 4; ++p)
    bp[p] = Bsrc + (size_t)(nb + wave * 32 + p * 8 + sr) * 1024 + gl * 8;

  for (int kt = 0; kt < 16; ++kt) {
    __syncthreads();
    #pragma unroll
    for (int p = 0; p < PA; ++p) {
      if (MODE == 2) {
        // stage A = p0 + p1 (combine attention halves in-flight)
        f16x8 a0 = *(const f16x8*)ap[p];
        f16x8 a1 = *(const f16x8*)ap2[p];
        *(f16x8*)&As[(wave * (TM / 4) + p * 8) * 64 + lane * 8] = a0 + a1;
        ap2[p] += 64;
      } else {
        gl_lds16(ap[p], &As[(wave * (TM / 4) + p * 8) * 64]);
      }
      ap[p] += 64;
    }
    #pragma unroll
    for (int p = 0; p < 4; ++p) {
      gl_lds16(bp[p], &Bs[(wave * 32 + p * 8) * 64]);
      bp[p] += 64;
    }
    __syncthreads();
    #pragma unroll
    for (int ks = 0; ks < 2; ++ks) {
      f16x8 af[NI], bf[4];
      #pragma unroll
      for (int i = 0; i < NI; ++i) {
        int row = wm + i * 16 + l15;
        int g2 = (ks * 4 + quad) ^ (row & 7);
        af[i] = *(const f16x8*)&As[row * 64 + g2 * 8];
      }
      #pragma unroll
      for (int j = 0; j < 4; ++j) {
        int row = wn + j * 16 + l15;
        int g2 = (ks * 4 + quad) ^ (row & 7);
        bf[j] = *(const f16x8*)&Bs[row * 64 + g2 * 8];
      }
      #pragma unroll
      for (int i = 0; i < NI; ++i)
        #pragma unroll
        for (int j = 0; j < 4; ++j)
          acc[i][j] = __builtin_amdgcn_mfma_f32_16x16x32_f16(af[i], bf[j], acc[i][j], 0, 0, 0);
    }
  }

  if (MODE == 0) {
    if (n0 < 2048) {
      __syncthreads();   // all waves done reading As/Bs before EP overlays them
      f16* ep = &EPb[wave * 64 * 72];
      #pragma unroll
      for (int i = 0; i < NI; ++i)
        #pragma unroll
        for (int j = 0; j < 4; ++j)
          #pragma unroll
          for (int r = 0; r < 4; ++r)
            ep[(i * 16 + quad * 4 + r) * 72 + j * 16 + l15] = (f16)acc[i][j][r];
      f16* dst = (n0 < 1024) ? (f16*)out0 : (f16*)out1;
      const int hh = ((n0 + wn) & 1023) >> 6;
      const int r8 = lane >> 3, cg = lane & 7;
      #pragma unroll
      for (int it = 0; it < 8; ++it) {
        int row = it * 8 + r8;
        f16x8 vv = *(const f16x8*)&ep[row * 72 + cg * 8];
        int m = m0 + wm + row;
        int b = m >> 10, t = m & 1023;
        *(f16x8*)&dst[(size_t)((b * 16 + hh) * 1024 + t) * 64 + cg * 8] = vv;
      }
    } else {
      #pragma unroll
      for (int i = 0; i < NI; ++i)
        #pragma unroll
        for (int j = 0; j < 4; ++j) {
          int mb = m0 + wm + i * 16 + quad * 4;
          int b = mb >> 10, t = mb & 1023;
          int n = n0 + wn + j * 16 + l15;
          int nn2 = n & 1023, hh = nn2 >> 6, d = nn2 & 63;
          f16x4 vv = { (f16)acc[i][j][0], (f16)acc[i][j][1], (f16)acc[i][j][2], (f16)acc[i][j][3] };
          *(f16x4*)((f16*)out2 + ((size_t)(b * 16 + hh) * 64 + d) * 1024 + t) = vv;
        }
    }
  } else {
    #pragma unroll
    for (int i = 0; i < NI; ++i)
      #pragma unroll
      for (int j = 0; j < 4; ++j)
        #pragma unroll
        for (int r = 0; r < 4; ++r) {
          int m = m0 + wm + i * 16 + quad * 4 + r;
          int n = n0 + wn + j * 16 + l15;
          ((float*)out0)[(size_t)m * 1024 + n] = acc[i][j][r];
        }
  }
}

// ---------------- fused sparse attention (half the chunks per block) ----------------
// S computed TRANSPOSED (mfma(K,Q)). Top-32 via 13-step packed-u16 bisection
// (proven R3/R5). R8:
//  * Q held in REGISTERS (wave-private; per-lane fragment = 2 contiguous 16B
//    global loads) -> Qs LDS eliminated.
//  * P never touches LDS: cvt_pk pairs pw[8] redistributed across the 4 quads
//    with 4x (permlane32_swap + permlane16_swap); resulting [pw0..3]/[pw4..7]
//    are exactly the PV A-operand fragments (exact permutation, bit-identical).
//  * LDS = K dbuf 16K + V 8K = 24 KiB -> 5-6 blocks/CU.
//  K dbuf + single-buffer V with counted vmcnt (R7), XCD swizzle (R6).
__global__ __launch_bounds__(256, 5)
void k_attn(const f16* __restrict__ Q16, const f16* __restrict__ K16, const f16* __restrict__ Vt16,
            const float* __restrict__ imp, const float* __restrict__ temps,
            f16* __restrict__ part0, f16* __restrict__ part1) {
  __shared__ __align__(16) f16 KsB[2][64 * 64];
  __shared__ __align__(16) f16 Vs[64 * 64];

  // XCD swizzle (grid = 2048 = 8 * 256, bijective)
  const int orig = ((int)blockIdx.x & 7) * 256 + ((int)blockIdx.x >> 3);
  const int bid = orig & 1023;
  const int half = orig >> 10;
  const int b = bid >> 8, h = (bid >> 4) & 15, qt = bid & 15;
  const int bh = b * 16 + h;
  const int tid = threadIdx.x, wave = tid >> 6, lane = tid & 63;
  const int l15 = lane & 15, quad = lane >> 4;

  // per-lane query-row scale (row m = wave*16 + l15)
  float sc = (0.125f * 1.44269504088896340736f) / fminf(fmaxf(temps[bh], 0.1f), 100.0f);
  const int tq = qt * 64 + wave * 16 + l15;
  float is = imp[(size_t)(b * 1024 + tq) * 16 + h];
  float s1 = 1.0f / (1.0f + __expf(-is));
  float mwv = 1.0f / (1.0f + __expf(-(s1 - 0.5f) * 10.0f));
  const float rs = sc * mwv;

  const unsigned vones = 0x00010001u;   // packed (1,1) for pk_min

  const int sr = lane >> 3, sg = lane & 7;
  const int gls = sg ^ sr;
  const size_t qoff = ((size_t)bh * 1024 + qt * 64) * 64;

  const size_t kbase = (size_t)bh * 1024 * 64;
  const size_t vbase = (size_t)bh * 64 * 1024;
  const f16* kp0 = K16 + kbase + (size_t)(half * 512 + wave * 16 + sr) * 64 + gls * 8;
  const f16* kp1 = kp0 + 8 * 64;
  const f16* vp0 = Vt16 + vbase + (size_t)(wave * 16 + sr) * 1024 + half * 512 + gls * 8;
  const f16* vp1 = vp0 + 8 * 1024;

  // prologue: Q fragment -> regs (2 loads), K(0) -> LDS (2 loads); 4 outstanding
  const f16* qp = Q16 + qoff + (size_t)(wave * 16 + l15) * 64 + quad * 8;
  f16x8 qf[2];
  qf[0] = *(const f16x8*)qp;          // ks=0: cols quad*8 .. +7
  qf[1] = *(const f16x8*)(qp + 32);   // ks=1: cols 32+quad*8 .. +7
  gl_lds16(kp0, &KsB[0][(wave * 16) * 64]);
  gl_lds16(kp1, &KsB[0][(wave * 16 + 8) * 64]);
  kp0 += 4096; kp1 += 4096;

  f32x4 oacc[4] = {};

  for (int ck = 0; ck < 8; ++ck) {
    const int cur = ck & 1, nxt = cur ^ 1;
    // B1: all waves finished PV(ck-1) (Vs free) and QK(ck-1) (KsB[nxt] free)
    __builtin_amdgcn_s_barrier();
    // issue V(ck) -> Vs (single buffer), then K(ck+1) -> KsB[nxt]
    gl_lds16(vp0, &Vs[(wave * 16) * 64]);
    gl_lds16(vp1, &Vs[(wave * 16 + 8) * 64]);
    vp0 += 64; vp1 += 64;
    if (ck < 7) {
      gl_lds16(kp0, &KsB[nxt][(wave * 16) * 64]);
      gl_lds16(kp1, &KsB[nxt][(wave * 16 + 8) * 64]);
      kp0 += 4096; kp1 += 4096;
      // K(ck) (and ck==0: Q regs) drained; V(ck):2 + K(ck+1):2 stay in flight
      asm volatile("s_waitcnt vmcnt(4)" ::: "memory");
    } else {
      // only V(7):2 in flight; K(7) drained
      asm volatile("s_waitcnt vmcnt(2)" ::: "memory");
    }
    __builtin_amdgcn_sched_barrier(0);
    // B2: every wave's K(ck) staging visible
    __builtin_amdgcn_s_barrier();

    const f16* Kc = &KsB[cur][0];

    // ---- S^T = K x Q^T : sacc[j][r] = S[c = j*16+quad*4+r][m = l15] ----
    f32x4 sacc[4] = {};
    #pragma unroll
    for (int ks = 0; ks < 2; ++ks) {
      #pragma unroll
      for (int j = 0; j < 4; ++j) {
        int kr = j * 16 + l15;
        int gk = (ks * 4 + quad) ^ (kr & 7);
        f16x8 ak = *(const f16x8*)&Kc[kr * 64 + gk * 8];
        sacc[j] = __builtin_amdgcn_mfma_f32_16x16x32_f16(ak, qf[ks], sacc[j], 0, 0, 0);
      }
    }

    // ---- biased clamp: xx = med3(fma(s, rs, 192), 132, 252) in [132,252] ----
    float xx[4][4];
    #pragma unroll
    for (int j = 0; j < 4; ++j)
      #pragma unroll
      for (int r = 0; r < 4; ++r)
        xx[j][r] = __builtin_amdgcn_fmed3f(__builtin_fmaf(sacc[j][r], rs, 192.0f), 132.0f, 252.0f);

    // ---- pack 16 keys to 8 x u16x2: k16 = (bits(xx) >> 10) & 0xffff ----
    unsigned pk16[8];
    #pragma unroll
    for (int j = 0; j < 4; ++j) {
      unsigned a0 = __builtin_bit_cast(unsigned, xx[j][0]) >> 10;
      unsigned a1 = __builtin_bit_cast(unsigned, xx[j][1]) >> 10;
      unsigned a2 = __builtin_bit_cast(unsigned, xx[j][2]) >> 10;
      unsigned a3 = __builtin_bit_cast(unsigned, xx[j][3]) >> 10;
      pk16[j * 2 + 0] = __builtin_amdgcn_perm(a1, a0, 0x05040100);
      pk16[j * 2 + 1] = __builtin_amdgcn_perm(a3, a2, 0x05040100);
    }

    // ---- top-32 threshold: 13-step bisection, packed counting ----
    unsigned tkp = 0xC000C000u;
    #pragma unroll
    for (int bit = 12; bit >= 0; --bit) {
      const unsigned cand = tkp | ((1u << bit) | (1u << (bit + 16)));
      const unsigned cm1 = cand - 0x00010001u;   // halves >= 0xC001, no inter-half borrow
      unsigned acc = 0;
      #pragma unroll
      for (int i = 0; i < 8; ++i)
        acc += pk_cnt_ge(pk16[i], cm1, vones);   // halves accumulate independently (<= 8)
      unsigned q = quadsum_u(acc);               // packed quad-sum: halves <= 32
      unsigned tot2 = q + (q << 16);             // top half = lo+hi (<= 64, no overflow)
      tkp = (tot2 >= (32u << 16)) ? cand : tkp;
    }
    const unsigned tk32 = 0x43000000u | ((tkp & 0x1fffu) << 10);

    // ---- masked softmax (masked -> exp2(0)=1, exact) ----
    float e[4][4];
    #pragma unroll
    for (int j = 0; j < 4; ++j)
      #pragma unroll
      for (int r = 0; r < 4; ++r) {
        float sel = (__builtin_bit_cast(unsigned, xx[j][r]) >= tk32) ? xx[j][r] : 192.0f;
        e[j][r] = EXP2(sel - 192.0f);
      }
    float dsum = ((e[0][0] + e[0][1]) + (e[0][2] + e[0][3]))
               + ((e[1][0] + e[1][1]) + (e[1][2] + e[1][3]))
               + ((e[2][0] + e[2][1]) + (e[2][2] + e[2][3]))
               + ((e[3][0] + e[3][1]) + (e[3][2] + e[3][3]));
    dsum = quadsum_f(dsum);
    const float dinv = __builtin_amdgcn_rcpf(dsum);

    // ---- P -> f16 pairs in regs: pw[2j+i] = pair p = 8j + 2*quad + i ----
    unsigned pw[8];
    #pragma unroll
    for (int j = 0; j < 4; ++j) {
      pw[2 * j]     = cvt_pk_u32(e[j][0] * dinv, e[j][1] * dinv);
      pw[2 * j + 1] = cvt_pk_u32(e[j][2] * dinv, e[j][3] * dinv);
    }
    // quad redistribution: pairings (0,2),(1,3),(4,6),(5,7); per pairing
    // swap32 then swap16 turns (u,w) into the consumer A-operand regs:
    // u' = (u0,u2,w0,w2), w' = (u1,u3,w1,w3) across quads (rows).
    #pragma unroll
    for (int t2 = 0; t2 < 4; ++t2) {
      const int ui = (t2 >> 1) * 4 + (t2 & 1);   // 0,1,4,5
      asm("s_nop 1\n\tv_permlane32_swap_b32 %0, %1" : "+v"(pw[ui]), "+v"(pw[ui + 2]));
      asm("s_nop 1\n\tv_permlane16_swap_b32 %0, %1" : "+v"(pw[ui]), "+v"(pw[ui + 2]));
    }

    // own V(ck) complete (only K(ck+1) outstanding); B3 publishes all waves' V
    if (ck < 7) {
      asm volatile("s_waitcnt vmcnt(2)" ::: "memory");
    } else {
      asm volatile("s_waitcnt vmcnt(0)" ::: "memory");
    }
    __builtin_amdgcn_sched_barrier(0);
    __builtin_amdgcn_s_barrier();

    // ---- O += P x V (A-operand straight from pw regs) ----
    #pragma unroll
    for (int ks = 0; ks < 2; ++ks) {
      uint4v aw = { pw[ks * 4 + 0], pw[ks * 4 + 1], pw[ks * 4 + 2], pw[ks * 4 + 3] };
      f16x8 ap2 = __builtin_bit_cast(f16x8, aw);
      #pragma unroll
      for (int j = 0; j < 4; ++j) {
        int rn = j * 16 + l15;
        int gn = (ks * 4 + quad) ^ (rn & 7);
        f16x8 bv = *(const f16x8*)&Vs[rn * 64 + gn * 8];
        oacc[j] = __builtin_amdgcn_mfma_f32_16x16x32_f16(ap2, bv, oacc[j], 0, 0, 0);
      }
    }
  }

  // raw partial; 1/16 is folded into Wot, halves combined in k_gemm<2> staging
  f16* pd = half ? part1 : part0;
  #pragma unroll
  for (int j = 0; j < 4; ++j)
    #pragma unroll
    for (int r = 0; r < 4; ++r) {
      int m = wave * 16 + quad * 4 + r;
      int t = qt * 64 + m;
      int d = j * 16 + l15;
      pd[(size_t)(b * 1024 + t) * 1024 + h * 64 + d] = (f16)oacc[j][r];
    }
}

extern "C" void kernel_launch(void* const* d_in, const int* in_sizes, int n_in,
                              void* d_out, int out_size, void* d_ws, size_t ws_size,
                              hipStream_t stream) {
  (void)in_sizes; (void)n_in; (void)out_size; (void)ws_size;
  const float* x     = (const float*)d_in[0];
  const float* imp   = (const float*)d_in[1];
  const float* temps = (const float*)d_in[2];
  const float* Wq    = (const float*)d_in[3];
  const float* Wk    = (const float*)d_in[4];
  const float* Wv    = (const float*)d_in[5];
  const float* Wo    = (const float*)d_in[6];
  float* out = (float*)d_out;

  char* w = (char*)d_ws;   // 48 MB
  f16* xh   = (f16*)w; w += (size_t)4096 * 1024 * 2;   // reused as attn part0
  f16* Wqt  = (f16*)w; w += (size_t)1024 * 1024 * 2;
  f16* Wkt  = (f16*)w; w += (size_t)1024 * 1024 * 2;
  f16* Wvt  = (f16*)w; w += (size_t)1024 * 1024 * 2;
  f16* Wot  = (f16*)w; w += (size_t)1024 * 1024 * 2;   // pre-scaled by 1/16
  f16* Q16  = (f16*)w; w += (size_t)4096 * 1024 * 2;
  f16* K16  = (f16*)w; w += (size_t)4096 * 1024 * 2;
  f16* Vt16 = (f16*)w; w += (size_t)4096 * 1024 * 2;
  f16* O16  = (f16*)w; w += (size_t)4096 * 1024 * 2;   // attn part1

  k_prep<<<dim3(16, 16, 5), dim3(256), 0, stream>>>(x, Wq, Wk, Wv, Wo, xh, Wqt, Wkt, Wvt, Wot);
  k_gemm<0, 128><<<dim3(24, 32), dim3(256), 0, stream>>>(xh, Wqt, nullptr, Wvt, Wkt,
                                                         (void*)Q16, (void*)K16, (void*)Vt16);
  k_attn<<<dim3(2048), dim3(256), 0, stream>>>(Q16, K16, Vt16, imp, temps, xh, O16);
  k_gemm<2, 64><<<dim3(8, 64), dim3(256), 0, stream>>>(xh, Wot, O16, nullptr, nullptr,
                                                       (void*)out, nullptr, nullptr);
}

// Round 9
// 221.061 us; speedup vs baseline: 1.0286x; 1.0260x over previous
//
#include <hip/hip_runtime.h>
#include <stdint.h>

typedef _Float16 f16;
typedef _Float16 f16x8 __attribute__((ext_vector_type(8)));
typedef _Float16 f16x4 __attribute__((ext_vector_type(4)));
typedef float f32x4 __attribute__((ext_vector_type(4)));
typedef unsigned uint2v __attribute__((ext_vector_type(2)));

#define AS1 __attribute__((address_space(1)))
#define AS3 __attribute__((address_space(3)))

#if __has_builtin(__builtin_amdgcn_exp2f)
#define EXP2(x) __builtin_amdgcn_exp2f(x)
#else
#define EXP2(x) exp2f(x)
#endif

__device__ __forceinline__ void gl_lds16(const void* g, void* l) {
  __builtin_amdgcn_global_load_lds((const AS1 uint32_t*)g, (AS3 uint32_t*)l, 16, 0, 0);
}

// sum over the 4 lanes {l, l^16, l^32, l^48} holding the same query row
// (proven: inline-asm permlane swaps with conservative hazard nops)
__device__ __forceinline__ unsigned quadsum_u(unsigned v) {
  unsigned a = v, b = v;
  asm("s_nop 1\n\tv_permlane16_swap_b32 %0, %1" : "+v"(a), "+v"(b));
  unsigned s = a + b;
  unsigned a2 = s, b2 = s;
  asm("s_nop 1\n\tv_permlane32_swap_b32 %0, %1" : "+v"(a2), "+v"(b2));
  return a2 + b2;
}
__device__ __forceinline__ float quadsum_f(float v) {
  float a = v, b = v;
  asm("s_nop 1\n\tv_permlane16_swap_b32 %0, %1" : "+v"(a), "+v"(b));
  float s = a + b;
  float a2 = s, b2 = s;
  asm("s_nop 1\n\tv_permlane32_swap_b32 %0, %1" : "+v"(a2), "+v"(b2));
  return a2 + b2;
}

// packed-u16 count: per half, returns (k >= cm1+1) ? 1 : 0. (proven in R3)
__device__ __forceinline__ unsigned pk_cnt_ge(unsigned k, unsigned cm1, unsigned ones) {
  unsigned d;
  asm("v_pk_sub_u16 %0, %1, %2 clamp" : "=v"(d) : "v"(k), "v"(cm1));
  asm("v_pk_min_u16 %0, %1, %2" : "=v"(d) : "v"(d), "v"(ones));
  return d;
}

// pack two floats to f16x2 bits (RTZ), returned as u32
__device__ __forceinline__ unsigned cvt_pk_u32(float a, float b) {
  return __builtin_bit_cast(unsigned, __builtin_amdgcn_cvt_pkrtz(a, b));
}

// ---------- fused prep: z=0..3 -> W transpose+cvt (Wo scaled 1/16); z=4 -> x cvt ----------
__global__ void k_prep(const float* __restrict__ x,
                       const float* __restrict__ Wq, const float* __restrict__ Wk,
                       const float* __restrict__ Wv, const float* __restrict__ Wo,
                       f16* __restrict__ xh,
                       f16* __restrict__ Wqt, f16* __restrict__ Wkt,
                       f16* __restrict__ Wvt, f16* __restrict__ Wot) {
  __shared__ __align__(16) f16 lt[64][72];
  const int t = threadIdx.x;
  if (blockIdx.z == 4) {
    int bid2 = blockIdx.y * 16 + blockIdx.x;
    #pragma unroll 4
    for (int it = 0; it < 16; ++it) {
      int i = ((bid2 * 16 + it) * 256 + t) * 4;
      float4 v = *(const float4*)(x + i);
      f16x4 o = { (f16)v.x, (f16)v.y, (f16)v.z, (f16)v.w };
      *(f16x4*)(xh + i) = o;
    }
    return;
  }
  const float* src; f16* dst; float scl;
  switch (blockIdx.z) {
    case 0: src = Wq; dst = Wqt; scl = 1.0f; break;
    case 1: src = Wk; dst = Wkt; scl = 1.0f; break;
    case 2: src = Wv; dst = Wvt; scl = 1.0f; break;
    default: src = Wo; dst = Wot; scl = 0.0625f; break;   // fold attn 1/16 into Wo
  }
  int n0 = blockIdx.x * 64, k0 = blockIdx.y * 64;
  int kk = t >> 4;
  int nn = (t & 15) * 4;
  #pragma unroll
  for (int p = 0; p < 4; ++p) {
    int k = kk + p * 16;
    float4 v = *(const float4*)(src + (size_t)(k0 + k) * 1024 + n0 + nn);
    lt[nn + 0][k] = (f16)(v.x * scl);
    lt[nn + 1][k] = (f16)(v.y * scl);
    lt[nn + 2][k] = (f16)(v.z * scl);
    lt[nn + 3][k] = (f16)(v.w * scl);
  }
  __syncthreads();
  int row = t >> 2;
  int kp = (t & 3) * 16;
  f16* d = dst + (size_t)(n0 + row) * 1024 + k0 + kp;
  *(f16x8*)d       = *(const f16x8*)&lt[row][kp];
  *(f16x8*)(d + 8) = *(const f16x8*)&lt[row][kp + 8];
}

// ---------------- GEMM: C(TMxN128 per block) = A * Bt^T ----------------
// MODE 0, TM=128: A=xh; Bt0/1/2=Wqt/Wkt/Wvt; N=3072; grid(24,32).
//   LDS: As+Bs (32 KiB) UNION'd with EP (36 KiB, epilogue-only, barrier-guarded).
// MODE 2, TM=64:  A=p0, A2=p1 (attention halves; staged as p0+p1); Bt0=Wot/16;
//                 out0 = f32 row-major. grid(8,64).
template<int MODE, int TM>
__global__ __launch_bounds__(256, 3)
void k_gemm(const f16* __restrict__ A, const f16* __restrict__ Bt0,
            const f16* __restrict__ A2, const f16* __restrict__ Bt2,
            const f16* __restrict__ Bt1,
            void* __restrict__ out0, void* __restrict__ out1, void* __restrict__ out2) {
  constexpr int SMEM_MAIN = TM * 64 * 2 + 128 * 64 * 2;
  constexpr int SMEM_EP = (MODE == 0) ? 4 * 64 * 72 * 2 : 0;
  constexpr int SMEM_SZ = SMEM_EP > SMEM_MAIN ? SMEM_EP : SMEM_MAIN;
  __shared__ __align__(16) char smem[SMEM_SZ];
  f16* As = (f16*)smem;
  f16* Bs = (f16*)(smem + TM * 64 * 2);
  f16* EPb = (f16*)smem;
  const int n0 = blockIdx.x * 128, m0 = blockIdx.y * TM;
  const int tid = threadIdx.x, wave = tid >> 6, lane = tid & 63;
  const int l15 = lane & 15, quad = lane >> 4;
  const int wm = (wave >> 1) * (TM / 2), wn = (wave & 1) * 64;
  constexpr int NI = TM / 32;
  constexpr int PA = TM / 32;
  const f16* Bsrc = Bt0;
  int nb = n0;
  if (MODE == 0) {
    if (n0 >= 2048)      { Bsrc = Bt2; nb = n0 - 2048; }
    else if (n0 >= 1024) { Bsrc = Bt1; nb = n0 - 1024; }
  }
  f32x4 acc[NI][4] = {};
  const int sr = lane >> 3, sg = lane & 7;
  const int gl = sg ^ sr;
  const f16* ap[PA];
  const f16* ap2[PA];
  const f16* bp[4];
  #pragma unroll
  for (int p = 0; p < PA; ++p) {
    size_t off = (size_t)(m0 + wave * (TM / 4) + p * 8 + sr) * 1024 + gl * 8;
    ap[p] = A + off;
    if (MODE == 2) ap2[p] = A2 + off;
  }
  #pragma unroll
  for (int p = 0; p < 4; ++p)
    bp[p] = Bsrc + (size_t)(nb + wave * 32 + p * 8 + sr) * 1024 + gl * 8;

  for (int kt = 0; kt < 16; ++kt) {
    __syncthreads();
    #pragma unroll
    for (int p = 0; p < PA; ++p) {
      if (MODE == 2) {
        // stage A = p0 + p1 (combine attention halves in-flight)
        f16x8 a0 = *(const f16x8*)ap[p];
        f16x8 a1 = *(const f16x8*)ap2[p];
        *(f16x8*)&As[(wave * (TM / 4) + p * 8) * 64 + lane * 8] = a0 + a1;
        ap2[p] += 64;
      } else {
        gl_lds16(ap[p], &As[(wave * (TM / 4) + p * 8) * 64]);
      }
      ap[p] += 64;
    }
    #pragma unroll
    for (int p = 0; p < 4; ++p) {
      gl_lds16(bp[p], &Bs[(wave * 32 + p * 8) * 64]);
      bp[p] += 64;
    }
    __syncthreads();
    #pragma unroll
    for (int ks = 0; ks < 2; ++ks) {
      f16x8 af[NI], bf[4];
      #pragma unroll
      for (int i = 0; i < NI; ++i) {
        int row = wm + i * 16 + l15;
        int g2 = (ks * 4 + quad) ^ (row & 7);
        af[i] = *(const f16x8*)&As[row * 64 + g2 * 8];
      }
      #pragma unroll
      for (int j = 0; j < 4; ++j) {
        int row = wn + j * 16 + l15;
        int g2 = (ks * 4 + quad) ^ (row & 7);
        bf[j] = *(const f16x8*)&Bs[row * 64 + g2 * 8];
      }
      #pragma unroll
      for (int i = 0; i < NI; ++i)
        #pragma unroll
        for (int j = 0; j < 4; ++j)
          acc[i][j] = __builtin_amdgcn_mfma_f32_16x16x32_f16(af[i], bf[j], acc[i][j], 0, 0, 0);
    }
  }

  if (MODE == 0) {
    if (n0 < 2048) {
      __syncthreads();   // all waves done reading As/Bs before EP overlays them
      f16* ep = &EPb[wave * 64 * 72];
      #pragma unroll
      for (int i = 0; i < NI; ++i)
        #pragma unroll
        for (int j = 0; j < 4; ++j)
          #pragma unroll
          for (int r = 0; r < 4; ++r)
            ep[(i * 16 + quad * 4 + r) * 72 + j * 16 + l15] = (f16)acc[i][j][r];
      f16* dst = (n0 < 1024) ? (f16*)out0 : (f16*)out1;
      const int hh = ((n0 + wn) & 1023) >> 6;
      const int r8 = lane >> 3, cg = lane & 7;
      #pragma unroll
      for (int it = 0; it < 8; ++it) {
        int row = it * 8 + r8;
        f16x8 vv = *(const f16x8*)&ep[row * 72 + cg * 8];
        int m = m0 + wm + row;
        int b = m >> 10, t = m & 1023;
        *(f16x8*)&dst[(size_t)((b * 16 + hh) * 1024 + t) * 64 + cg * 8] = vv;
      }
    } else {
      #pragma unroll
      for (int i = 0; i < NI; ++i)
        #pragma unroll
        for (int j = 0; j < 4; ++j) {
          int mb = m0 + wm + i * 16 + quad * 4;
          int b = mb >> 10, t = mb & 1023;
          int n = n0 + wn + j * 16 + l15;
          int nn2 = n & 1023, hh = nn2 >> 6, d = nn2 & 63;
          f16x4 vv = { (f16)acc[i][j][0], (f16)acc[i][j][1], (f16)acc[i][j][2], (f16)acc[i][j][3] };
          *(f16x4*)((f16*)out2 + ((size_t)(b * 16 + hh) * 64 + d) * 1024 + t) = vv;
        }
    }
  } else {
    #pragma unroll
    for (int i = 0; i < NI; ++i)
      #pragma unroll
      for (int j = 0; j < 4; ++j)
        #pragma unroll
        for (int r = 0; r < 4; ++r) {
          int m = m0 + wm + i * 16 + quad * 4 + r;
          int n = n0 + wn + j * 16 + l15;
          ((float*)out0)[(size_t)m * 1024 + n] = acc[i][j][r];
        }
  }
}

// ---------------- fused sparse attention (half the chunks per block) ----------------
// S computed TRANSPOSED (mfma(K,Q)). Top-32 via 13-step packed-u16 bisection
// (proven R3/R5). R9 = R7 loop (P through LDS — LDS-pipe ops are free for this
// VALU-issue-bound kernel; R8 proved permlane-P costs more) + Q in REGISTERS
// (R8-proven, zero VALU cost, kills Qs + 2 ds_reads/chunk).
// K dbuf + single-buffer V with counted vmcnt (R7), XCD swizzle (R6).
// LDS = K dbuf 16K + Vs 8K + Ps 8K = 32 KiB.
__global__ __launch_bounds__(256, 4)
void k_attn(const f16* __restrict__ Q16, const f16* __restrict__ K16, const f16* __restrict__ Vt16,
            const float* __restrict__ imp, const float* __restrict__ temps,
            f16* __restrict__ part0, f16* __restrict__ part1) {
  __shared__ __align__(16) f16 KsB[2][64 * 64];
  __shared__ __align__(16) f16 Vs[64 * 64];
  __shared__ __align__(16) f16 Ps[64 * 64];

  // XCD swizzle (grid = 2048 = 8 * 256, bijective)
  const int orig = ((int)blockIdx.x & 7) * 256 + ((int)blockIdx.x >> 3);
  const int bid = orig & 1023;
  const int half = orig >> 10;
  const int b = bid >> 8, h = (bid >> 4) & 15, qt = bid & 15;
  const int bh = b * 16 + h;
  const int tid = threadIdx.x, wave = tid >> 6, lane = tid & 63;
  const int l15 = lane & 15, quad = lane >> 4;

  // per-lane query-row scale (row m = wave*16 + l15)
  float sc = (0.125f * 1.44269504088896340736f) / fminf(fmaxf(temps[bh], 0.1f), 100.0f);
  const int tq = qt * 64 + wave * 16 + l15;
  float is = imp[(size_t)(b * 1024 + tq) * 16 + h];
  float s1 = 1.0f / (1.0f + __expf(-is));
  float mwv = 1.0f / (1.0f + __expf(-(s1 - 0.5f) * 10.0f));
  const float rs = sc * mwv;

  const unsigned vones = 0x00010001u;   // packed (1,1) for pk_min

  const int sr = lane >> 3, sg = lane & 7;
  const int gls = sg ^ sr;
  const size_t qoff = ((size_t)bh * 1024 + qt * 64) * 64;

  const size_t kbase = (size_t)bh * 1024 * 64;
  const size_t vbase = (size_t)bh * 64 * 1024;
  const f16* kp0 = K16 + kbase + (size_t)(half * 512 + wave * 16 + sr) * 64 + gls * 8;
  const f16* kp1 = kp0 + 8 * 64;
  const f16* vp0 = Vt16 + vbase + (size_t)(wave * 16 + sr) * 1024 + half * 512 + gls * 8;
  const f16* vp1 = vp0 + 8 * 1024;

  // prologue: Q fragment -> regs (2 loads), K(0) -> LDS (2 loads); 4 outstanding
  const f16* qp = Q16 + qoff + (size_t)(wave * 16 + l15) * 64 + quad * 8;
  f16x8 qf[2];
  qf[0] = *(const f16x8*)qp;          // ks=0: cols quad*8 .. +7
  qf[1] = *(const f16x8*)(qp + 32);   // ks=1: cols 32+quad*8 .. +7
  gl_lds16(kp0, &KsB[0][(wave * 16) * 64]);
  gl_lds16(kp1, &KsB[0][(wave * 16 + 8) * 64]);
  kp0 += 4096; kp1 += 4096;

  // hoisted P-store bases: value (m = wave*16+l15, c = j*16+quad*4+r) lands at
  // Ps[m*64 + ((c>>3)^(m&7))*8 + (c&7)]; the 4 r's are contiguous -> ds_write_b64
  const int mrow = wave * 16 + l15;
  f16* pst[4];
  #pragma unroll
  for (int j = 0; j < 4; ++j)
    pst[j] = &Ps[mrow * 64 + (((j * 2 + (quad >> 1)) ^ (l15 & 7)) * 8 + (quad & 1) * 4)];

  f32x4 oacc[4] = {};

  for (int ck = 0; ck < 8; ++ck) {
    const int cur = ck & 1, nxt = cur ^ 1;
    // B1: all waves finished PV(ck-1) (Vs free) and QK(ck-1) (KsB[nxt] free)
    __builtin_amdgcn_s_barrier();
    // issue V(ck) -> Vs (single buffer), then K(ck+1) -> KsB[nxt]
    gl_lds16(vp0, &Vs[(wave * 16) * 64]);
    gl_lds16(vp1, &Vs[(wave * 16 + 8) * 64]);
    vp0 += 64; vp1 += 64;
    if (ck < 7) {
      gl_lds16(kp0, &KsB[nxt][(wave * 16) * 64]);
      gl_lds16(kp1, &KsB[nxt][(wave * 16 + 8) * 64]);
      kp0 += 4096; kp1 += 4096;
      // K(ck) (and ck==0: Q regs) drained; V(ck):2 + K(ck+1):2 stay in flight
      asm volatile("s_waitcnt vmcnt(4)" ::: "memory");
    } else {
      // only V(7):2 in flight; K(7) drained
      asm volatile("s_waitcnt vmcnt(2)" ::: "memory");
    }
    __builtin_amdgcn_sched_barrier(0);
    // B2: every wave's K(ck) staging visible
    __builtin_amdgcn_s_barrier();

    const f16* Kc = &KsB[cur][0];

    // ---- S^T = K x Q^T : sacc[j][r] = S[c = j*16+quad*4+r][m = l15] ----
    f32x4 sacc[4] = {};
    #pragma unroll
    for (int ks = 0; ks < 2; ++ks) {
      #pragma unroll
      for (int j = 0; j < 4; ++j) {
        int kr = j * 16 + l15;
        int gk = (ks * 4 + quad) ^ (kr & 7);
        f16x8 ak = *(const f16x8*)&Kc[kr * 64 + gk * 8];
        sacc[j] = __builtin_amdgcn_mfma_f32_16x16x32_f16(ak, qf[ks], sacc[j], 0, 0, 0);
      }
    }

    // ---- biased clamp: xx = med3(fma(s, rs, 192), 132, 252) in [132,252] ----
    float xx[4][4];
    #pragma unroll
    for (int j = 0; j < 4; ++j)
      #pragma unroll
      for (int r = 0; r < 4; ++r)
        xx[j][r] = __builtin_amdgcn_fmed3f(__builtin_fmaf(sacc[j][r], rs, 192.0f), 132.0f, 252.0f);

    // ---- pack 16 keys to 8 x u16x2: k16 = (bits(xx) >> 10) & 0xffff ----
    unsigned pk16[8];
    #pragma unroll
    for (int j = 0; j < 4; ++j) {
      unsigned a0 = __builtin_bit_cast(unsigned, xx[j][0]) >> 10;
      unsigned a1 = __builtin_bit_cast(unsigned, xx[j][1]) >> 10;
      unsigned a2 = __builtin_bit_cast(unsigned, xx[j][2]) >> 10;
      unsigned a3 = __builtin_bit_cast(unsigned, xx[j][3]) >> 10;
      pk16[j * 2 + 0] = __builtin_amdgcn_perm(a1, a0, 0x05040100);
      pk16[j * 2 + 1] = __builtin_amdgcn_perm(a3, a2, 0x05040100);
    }

    // ---- top-32 threshold: 13-step bisection, packed counting ----
    unsigned tkp = 0xC000C000u;
    #pragma unroll
    for (int bit = 12; bit >= 0; --bit) {
      const unsigned cand = tkp | ((1u << bit) | (1u << (bit + 16)));
      const unsigned cm1 = cand - 0x00010001u;   // halves >= 0xC001, no inter-half borrow
      unsigned acc = 0;
      #pragma unroll
      for (int i = 0; i < 8; ++i)
        acc += pk_cnt_ge(pk16[i], cm1, vones);   // halves accumulate independently (<= 8)
      unsigned q = quadsum_u(acc);               // packed quad-sum: halves <= 32
      unsigned tot2 = q + (q << 16);             // top half = lo+hi (<= 64, no overflow)
      tkp = (tot2 >= (32u << 16)) ? cand : tkp;
    }
    const unsigned tk32 = 0x43000000u | ((tkp & 0x1fffu) << 10);

    // ---- masked softmax (masked -> exp2(0)=1, exact) ----
    float e[4][4];
    #pragma unroll
    for (int j = 0; j < 4; ++j)
      #pragma unroll
      for (int r = 0; r < 4; ++r) {
        float sel = (__builtin_bit_cast(unsigned, xx[j][r]) >= tk32) ? xx[j][r] : 192.0f;
        e[j][r] = EXP2(sel - 192.0f);
      }
    float dsum = ((e[0][0] + e[0][1]) + (e[0][2] + e[0][3]))
               + ((e[1][0] + e[1][1]) + (e[1][2] + e[1][3]))
               + ((e[2][0] + e[2][1]) + (e[2][2] + e[2][3]))
               + ((e[3][0] + e[3][1]) + (e[3][2] + e[3][3]));
    dsum = quadsum_f(dsum);
    const float dinv = __builtin_amdgcn_rcpf(dsum);

    // ---- P -> f16 (cvt_pkrtz pairs) into A-operand layout, 4x ds_write_b64 ----
    #pragma unroll
    for (int j = 0; j < 4; ++j) {
      uint2v pw = { cvt_pk_u32(e[j][0] * dinv, e[j][1] * dinv),
                    cvt_pk_u32(e[j][2] * dinv, e[j][3] * dinv) };
      *(f16x4*)pst[j] = __builtin_bit_cast(f16x4, pw);
    }

    // own V(ck) complete (only K(ck+1) outstanding); B3 publishes all waves' V
    if (ck < 7) {
      asm volatile("s_waitcnt vmcnt(2)" ::: "memory");
    } else {
      asm volatile("s_waitcnt vmcnt(0)" ::: "memory");
    }
    __builtin_amdgcn_sched_barrier(0);
    __builtin_amdgcn_s_barrier();

    // ---- O += P x V ----
    #pragma unroll
    for (int ks = 0; ks < 2; ++ks) {
      int row = wave * 16 + l15;
      int g2 = (ks * 4 + quad) ^ (row & 7);
      f16x8 ap2 = *(const f16x8*)&Ps[row * 64 + g2 * 8];
      #pragma unroll
      for (int j = 0; j < 4; ++j) {
        int rn = j * 16 + l15;
        int gn = (ks * 4 + quad) ^ (rn & 7);
        f16x8 bv = *(const f16x8*)&Vs[rn * 64 + gn * 8];
        oacc[j] = __builtin_amdgcn_mfma_f32_16x16x32_f16(ap2, bv, oacc[j], 0, 0, 0);
      }
    }
  }

  // raw partial; 1/16 is folded into Wot, halves combined in k_gemm<2> staging
  f16* pd = half ? part1 : part0;
  #pragma unroll
  for (int j = 0; j < 4; ++j)
    #pragma unroll
    for (int r = 0; r < 4; ++r) {
      int m = wave * 16 + quad * 4 + r;
      int t = qt * 64 + m;
      int d = j * 16 + l15;
      pd[(size_t)(b * 1024 + t) * 1024 + h * 64 + d] = (f16)oacc[j][r];
    }
}

extern "C" void kernel_launch(void* const* d_in, const int* in_sizes, int n_in,
                              void* d_out, int out_size, void* d_ws, size_t ws_size,
                              hipStream_t stream) {
  (void)in_sizes; (void)n_in; (void)out_size; (void)ws_size;
  const float* x     = (const float*)d_in[0];
  const float* imp   = (const float*)d_in[1];
  const float* temps = (const float*)d_in[2];
  const float* Wq    = (const float*)d_in[3];
  const float* Wk    = (const float*)d_in[4];
  const float* Wv    = (const float*)d_in[5];
  const float* Wo    = (const float*)d_in[6];
  float* out = (float*)d_out;

  char* w = (char*)d_ws;   // 48 MB
  f16* xh   = (f16*)w; w += (size_t)4096 * 1024 * 2;   // reused as attn part0
  f16* Wqt  = (f16*)w; w += (size_t)1024 * 1024 * 2;
  f16* Wkt  = (f16*)w; w += (size_t)1024 * 1024 * 2;
  f16* Wvt  = (f16*)w; w += (size_t)1024 * 1024 * 2;
  f16* Wot  = (f16*)w; w += (size_t)1024 * 1024 * 2;   // pre-scaled by 1/16
  f16* Q16  = (f16*)w; w += (size_t)4096 * 1024 * 2;
  f16* K16  = (f16*)w; w += (size_t)4096 * 1024 * 2;
  f16* Vt16 = (f16*)w; w += (size_t)4096 * 1024 * 2;
  f16* O16  = (f16*)w; w += (size_t)4096 * 1024 * 2;   // attn part1

  k_prep<<<dim3(16, 16, 5), dim3(256), 0, stream>>>(x, Wq, Wk, Wv, Wo, xh, Wqt, Wkt, Wvt, Wot);
  k_gemm<0, 128><<<dim3(24, 32), dim3(256), 0, stream>>>(xh, Wqt, nullptr, Wvt, Wkt,
                                                         (void*)Q16, (void*)K16, (void*)Vt16);
  k_attn<<<dim3(2048), dim3(256), 0, stream>>>(Q16, K16, Vt16, imp, temps, xh, O16);
  k_gemm<2, 64><<<dim3(8, 64), dim3(256), 0, stream>>>(xh, Wot, O16, nullptr, nullptr,
                                                       (void*)out, nullptr, nullptr);
}